// Round 14
// baseline (510.477 us; speedup 1.0000x reference)
//
#include <hip/hip_runtime.h>
#include <math.h>
#include <float.h>

#define NN 32768
#define NE 524288
#define NG 256
#define DD 64
#define NL 4
#define AVGDLOG 2.8332133340562162f
#define BN_EPS 1e-5f

// ---------------- init kernels ----------------

__global__ void k_embed(const int* __restrict__ h_tok, const float* __restrict__ emb_h,
                        float* __restrict__ h) {
    int t = blockIdx.x * 256 + threadIdx.x;   // NN*DD threads
    int n = t >> 6, j = t & 63;
    h[t] = emb_h[h_tok[n] * DD + j];
}

__global__ void k_deg(const int* __restrict__ dst, int* __restrict__ deg) {
    int e = blockIdx.x * 256 + threadIdx.x;
    if (e < NE) atomicAdd(&deg[dst[e]], 1);
}

__global__ __launch_bounds__(1024) void k_scan(const int* __restrict__ deg,
                                               int* __restrict__ row_start,
                                               int* __restrict__ cursor,
                                               float* __restrict__ amp,
                                               float* __restrict__ att,
                                               float* __restrict__ invdeg) {
    __shared__ int sd[1024];
    int t = threadIdx.x;
    int base = t * 32;
    int loc[32];
    int s = 0;
#pragma unroll
    for (int i = 0; i < 32; i++) { loc[i] = deg[base + i]; s += loc[i]; }
    sd[t] = s;
    __syncthreads();
    for (int off = 1; off < 1024; off <<= 1) {
        int v = (t >= off) ? sd[t - off] : 0;
        __syncthreads();
        sd[t] += v;
        __syncthreads();
    }
    int run = sd[t] - s;   // exclusive prefix
#pragma unroll
    for (int i = 0; i < 32; i++) {
        int idx = base + i;
        row_start[idx] = run;
        cursor[idx] = run;
        int dg = loc[i];
        float d = (float)dg;
        float logd = logf(d + 1.0f);
        amp[idx] = logd * (1.0f / AVGDLOG);
        att[idx] = AVGDLOG / fmaxf(logd, 1e-6f);
        invdeg[idx] = 1.0f / fmaxf(d, 1.0f);
        run += dg;
    }
    if (t == 1023) row_start[NN] = run;
}

__global__ void k_scatter(const int* __restrict__ src, const int* __restrict__ dst,
                          const int* __restrict__ e_tok, int* __restrict__ cursor,
                          int* __restrict__ csr) {
    int e = blockIdx.x * 256 + threadIdx.x;
    int d = dst[e];
    int p = atomicAdd(&cursor[d], 1);
    csr[p] = (src[e] << 3) | (e_tok[e] & 7);
}

// bond_msg[l][r][j] = b_pre[l][j] + sum_k emb_e[r][k] * W_pre[l][128+k][j]
__global__ void k_bond(const float* __restrict__ emb_e, const float* __restrict__ W_pre,
                       const float* __restrict__ b_pre, float* __restrict__ bond) {
    int t = blockIdx.x * 256 + threadIdx.x;   // NL*8*64 = 2048 threads
    int j = t & 63, r = (t >> 6) & 7, l = t >> 9;
    float s = b_pre[l * DD + j];
    const float* w = W_pre + (size_t)l * 192 * DD + 128 * DD + j;
    const float* e = emb_e + r * DD;
#pragma unroll
    for (int k = 0; k < DD; k++) s = fmaf(e[k], w[k * DD], s);
    bond[t] = s;
}

// ---------------- per-layer GEMM kernels ----------------
// k_A: r9 proven (256 thr, 4 rows x 4 cols, single K=64 phase, 53->13us class).
// k_C: two-group half-K design — 256 thr = 2 groups of 128; group g computes
// K rows [g*128, g*128+128) of the 64x64 tile with 8-row x 4-col blocking
// (0.83 B LDS per FMA, vs 1.33 at 4x4), 4 chunks of 32 K each, lockstep
// barriers. Group 1 deposits 24 acc float4s in LDS ([i][tl] layout, 2-way free);
// group 0 adds + epilogue. Keeps 8 waves/CU (r13's 8-row fix lost half of them).
// NO cross-loop register staging (spill: r5/r7/r10/r12). All accs NAMED float4s.

#define FMA4(acc, a, wv) \
    acc.x = fmaf(a, wv.x, acc.x); acc.y = fmaf(a, wv.y, acc.y); \
    acc.z = fmaf(a, wv.z, acc.z); acc.w = fmaf(a, wv.w, acc.w);

// A: ts = h@Wpre[0:64], td = h@Wpre[64:128], base = h@Wpost[0:64]. Single phase (K=64).
__global__ __launch_bounds__(256) void k_A(const float* __restrict__ h,
                                           const float* __restrict__ W_pre,
                                           const float* __restrict__ W_post, int l,
                                           float* __restrict__ ts, float* __restrict__ td,
                                           float* __restrict__ base_o) {
    __shared__ float wl[3 * 4096];   // [c][k 0..63][j 0..63] linear
    __shared__ float hl[64 * 68];    // [n 0..63][k 0..63] pad-stride 68
    int t = threadIdx.x;
    int j0 = (t & 15) << 2;
    int q4 = (t >> 4) << 2;
    int n0 = blockIdx.x * 64;
    const float* W0 = W_pre + (size_t)l * 192 * DD;
    const float* W1 = W0 + 64 * DD;
    const float* W2 = W_post + (size_t)l * 832 * DD;
#pragma unroll
    for (int s = 0; s < 12; ++s) {
        int g = s * 256 + t;             // 0..3071 f4 of W (3 x 64 x 16)
        int c = g >> 10;
        int k = (g >> 4) & 63;
        int c4 = (g & 15) << 2;
        const float* Wc = (c == 0) ? W0 : (c == 1 ? W1 : W2);
        *(float4*)&wl[c * 4096 + k * 64 + c4] = *(const float4*)&Wc[(size_t)k * 64 + c4];
    }
#pragma unroll
    for (int s = 0; s < 4; ++s) {
        int g = s * 256 + t;             // 0..1023 f4 of h tile
        int row = g >> 4;
        int c4 = (g & 15) << 2;
        *(float4*)&hl[row * 68 + c4] = *(const float4*)&h[(size_t)(n0 + row) * 64 + c4];
    }
    __syncthreads();
    float4 z4 = make_float4(0.f, 0.f, 0.f, 0.f);
    float4 c0_0 = z4, c0_1 = z4, c0_2 = z4, c0_3 = z4;
    float4 c1_0 = z4, c1_1 = z4, c1_2 = z4, c1_3 = z4;
    float4 c2_0 = z4, c2_1 = z4, c2_2 = z4, c2_3 = z4;
#pragma unroll
    for (int k4 = 0; k4 < 16; ++k4) {
        int ab = k4 << 2;
        float4 av0 = *(const float4*)&hl[(q4 + 0) * 68 + ab];
        float4 av1 = *(const float4*)&hl[(q4 + 1) * 68 + ab];
        float4 av2 = *(const float4*)&hl[(q4 + 2) * 68 + ab];
        float4 av3 = *(const float4*)&hl[(q4 + 3) * 68 + ab];
#define ASTEP(KK, COMP) { \
        int widx = (ab + KK) * 64 + j0; \
        float4 wv0 = *(const float4*)&wl[widx]; \
        float4 wv1 = *(const float4*)&wl[4096 + widx]; \
        float4 wv2 = *(const float4*)&wl[8192 + widx]; \
        FMA4(c0_0, av0.COMP, wv0) FMA4(c1_0, av0.COMP, wv1) FMA4(c2_0, av0.COMP, wv2) \
        FMA4(c0_1, av1.COMP, wv0) FMA4(c1_1, av1.COMP, wv1) FMA4(c2_1, av1.COMP, wv2) \
        FMA4(c0_2, av2.COMP, wv0) FMA4(c1_2, av2.COMP, wv1) FMA4(c2_2, av2.COMP, wv2) \
        FMA4(c0_3, av3.COMP, wv0) FMA4(c1_3, av3.COMP, wv1) FMA4(c2_3, av3.COMP, wv2) }
        ASTEP(0, x) ASTEP(1, y) ASTEP(2, z) ASTEP(3, w)
#undef ASTEP
    }
#define AOUT(I, A0, A1, A2) { \
    size_t n = (size_t)(n0 + q4 + I); \
    *(float4*)&ts[n * DD + j0] = A0; \
    *(float4*)&td[n * DD + j0] = A1; \
    *(float4*)&base_o[n * DD + j0] = A2; }
    AOUT(0, c0_0, c1_0, c2_0)
    AOUT(1, c0_1, c1_1, c2_1)
    AOUT(2, c0_2, c1_2, c2_2)
    AOUT(3, c0_3, c1_3, c2_3)
#undef AOUT
}

// B: per-node aggregation (one wave per node, lane = feature), 8-deep gather unroll
__global__ __launch_bounds__(256) void k_B(const float* __restrict__ ts,
                                           const float* __restrict__ td,
                                           const float* __restrict__ bond_l,
                                           const int* __restrict__ row_start,
                                           const int* __restrict__ csr,
                                           const float* __restrict__ invdeg,
                                           float* __restrict__ agg) {
    int t = threadIdx.x;
    int lane = t & 63;
    int q = __builtin_amdgcn_readfirstlane(t >> 6);
    int n = blockIdx.x * 4 + q;
    int rs = __builtin_amdgcn_readfirstlane(row_start[n]);
    int re = __builtin_amdgcn_readfirstlane(row_start[n + 1]);
    int cnt = re - rs;
    const int* cp = csr + rs;
    float tdv = td[(size_t)n * DD + lane];
    float s1 = 0.f, s2 = 0.f, mx = -FLT_MAX, mn = FLT_MAX;
    int i = 0;
    for (; i + 8 <= cnt; i += 8) {
        int p[8];
#pragma unroll
        for (int u = 0; u < 8; ++u) p[u] = cp[i + u];
        float m[8];
#pragma unroll
        for (int u = 0; u < 8; ++u) m[u] = ts[(size_t)(p[u] >> 3) * DD + lane];
#pragma unroll
        for (int u = 0; u < 8; ++u) m[u] += bond_l[((p[u] & 7) << 6) + lane] + tdv;
#pragma unroll
        for (int u = 0; u < 8; ++u) {
            s1 += m[u]; s2 = fmaf(m[u], m[u], s2);
            mx = fmaxf(mx, m[u]); mn = fminf(mn, m[u]);
        }
    }
    for (; i < cnt; i++) {
        int p0 = cp[i];
        float m0 = ts[(size_t)(p0 >> 3) * DD + lane] + bond_l[((p0 & 7) << 6) + lane] + tdv;
        s1 += m0; s2 = fmaf(m0, m0, s2); mx = fmaxf(mx, m0); mn = fminf(mn, m0);
    }
    float iv = invdeg[n];
    float mean = s1 * iv;
    float var = fmaxf(s2 * iv - mean * mean, 0.f);
    float sd = sqrtf(var + BN_EPS);
    bool has = cnt > 0;
    mx = has ? mx : 0.f;
    mn = has ? mn : 0.f;
    float* ao = agg + (size_t)n * 256;
    ao[lane] = mean;
    ao[64 + lane] = mx;
    ao[128 + lane] = mn;
    ao[192 + lane] = sd;
}

// C: h_pre = (base + b_post + agg@W1c + amp*(agg@W2c) + att*(agg@W3c)) * snorm ; BN partials
// Two-group half-K: group g (threads g*128..) computes K rows [g*128, g*128+128)
// in 4 chunks of 32; LDS combine at the end.
__global__ __launch_bounds__(256) void k_C(const float* __restrict__ agg,
                                           const float* __restrict__ base_i,
                                           const float* __restrict__ W_post,
                                           const float* __restrict__ b_post, int l,
                                           const float* __restrict__ amp,
                                           const float* __restrict__ att,
                                           const float* __restrict__ snorm,
                                           float* __restrict__ h_pre,
                                           float* __restrict__ bn_acc) {
    __shared__ float wl[2][3 * 2048];   // per-group W chunk [c][k 0..31][j 0..63]
    __shared__ float ag4[2][64 * 36];   // per-group agg chunk [n 0..63][k 0..31] pad-36
    int t = threadIdx.x;
    int g = t >> 7;                  // K-half group (wave-uniform)
    int tl = t & 127;
    int j0 = (tl & 15) << 2;
    int q8 = (tl >> 4) << 3;         // 0,8,...,56
    int n0 = blockIdx.x * 64;
    const float* Wp = W_post + (size_t)l * 832 * DD;
    float4 z4 = make_float4(0.f, 0.f, 0.f, 0.f);
    float4 c0_0 = z4, c0_1 = z4, c0_2 = z4, c0_3 = z4, c0_4 = z4, c0_5 = z4, c0_6 = z4, c0_7 = z4;
    float4 c1_0 = z4, c1_1 = z4, c1_2 = z4, c1_3 = z4, c1_4 = z4, c1_5 = z4, c1_6 = z4, c1_7 = z4;
    float4 c2_0 = z4, c2_1 = z4, c2_2 = z4, c2_3 = z4, c2_4 = z4, c2_5 = z4, c2_6 = z4, c2_7 = z4;

    for (int kc = 0; kc < 4; ++kc) {
        int kcs = (g << 2) + kc;     // global chunk id 0..7
        if (kc) __syncthreads();
#pragma unroll
        for (int s = 0; s < 12; ++s) {
            int gi = s * 128 + tl;        // 0..1535 f4 of W chunk (3 x 32 x 16)
            int c = gi >> 9;
            int k = (gi >> 4) & 31;
            int c4 = (gi & 15) << 2;
            int rowbase = (c == 0) ? 64 : (c == 1 ? 320 : 576);
            *(float4*)&wl[g][c * 2048 + k * 64 + c4] =
                *(const float4*)&Wp[(size_t)(rowbase + kcs * 32 + k) * 64 + c4];
        }
#pragma unroll
        for (int s = 0; s < 4; ++s) {
            int gi = s * 128 + tl;        // 0..511 f4 of agg chunk (64 x 8)
            int row = gi >> 3;
            int c4 = (gi & 7) << 2;
            *(float4*)&ag4[g][row * 36 + c4] =
                *(const float4*)&agg[(size_t)(n0 + row) * 256 + kcs * 32 + c4];
        }
        __syncthreads();
#pragma unroll
        for (int k4 = 0; k4 < 8; ++k4) {
            int ab = k4 << 2;
            float4 av0 = *(const float4*)&ag4[g][(q8 + 0) * 36 + ab];
            float4 av1 = *(const float4*)&ag4[g][(q8 + 1) * 36 + ab];
            float4 av2 = *(const float4*)&ag4[g][(q8 + 2) * 36 + ab];
            float4 av3 = *(const float4*)&ag4[g][(q8 + 3) * 36 + ab];
            float4 av4 = *(const float4*)&ag4[g][(q8 + 4) * 36 + ab];
            float4 av5 = *(const float4*)&ag4[g][(q8 + 5) * 36 + ab];
            float4 av6 = *(const float4*)&ag4[g][(q8 + 6) * 36 + ab];
            float4 av7 = *(const float4*)&ag4[g][(q8 + 7) * 36 + ab];
#define CSTEP(KK, COMP) { \
            int widx = (ab + KK) * 64 + j0; \
            float4 wv0 = *(const float4*)&wl[g][widx]; \
            float4 wv1 = *(const float4*)&wl[g][2048 + widx]; \
            float4 wv2 = *(const float4*)&wl[g][4096 + widx]; \
            FMA4(c0_0, av0.COMP, wv0) FMA4(c1_0, av0.COMP, wv1) FMA4(c2_0, av0.COMP, wv2) \
            FMA4(c0_1, av1.COMP, wv0) FMA4(c1_1, av1.COMP, wv1) FMA4(c2_1, av1.COMP, wv2) \
            FMA4(c0_2, av2.COMP, wv0) FMA4(c1_2, av2.COMP, wv1) FMA4(c2_2, av2.COMP, wv2) \
            FMA4(c0_3, av3.COMP, wv0) FMA4(c1_3, av3.COMP, wv1) FMA4(c2_3, av3.COMP, wv2) \
            FMA4(c0_4, av4.COMP, wv0) FMA4(c1_4, av4.COMP, wv1) FMA4(c2_4, av4.COMP, wv2) \
            FMA4(c0_5, av5.COMP, wv0) FMA4(c1_5, av5.COMP, wv1) FMA4(c2_5, av5.COMP, wv2) \
            FMA4(c0_6, av6.COMP, wv0) FMA4(c1_6, av6.COMP, wv1) FMA4(c2_6, av6.COMP, wv2) \
            FMA4(c0_7, av7.COMP, wv0) FMA4(c1_7, av7.COMP, wv1) FMA4(c2_7, av7.COMP, wv2) }
            CSTEP(0, x) CSTEP(1, y) CSTEP(2, z) CSTEP(3, w)
#undef CSTEP
        }
    }

    // ---- combine: group 1 -> LDS -> group 0 adds ----
    __syncthreads();
    float* cb = &wl[0][0];   // 12288 floats = 3072 f4 slots; need 24*128 = 3072 exactly
#define ACCL(X) \
    X(0, c0_0) X(1, c1_0) X(2, c2_0) X(3, c0_1) X(4, c1_1) X(5, c2_1) \
    X(6, c0_2) X(7, c1_2) X(8, c2_2) X(9, c0_3) X(10, c1_3) X(11, c2_3) \
    X(12, c0_4) X(13, c1_4) X(14, c2_4) X(15, c0_5) X(16, c1_5) X(17, c2_5) \
    X(18, c0_6) X(19, c1_6) X(20, c2_6) X(21, c0_7) X(22, c1_7) X(23, c2_7)
    if (g == 1) {
#define WRA(I, A) *(float4*)&cb[(I * 128 + tl) * 4] = A;
        ACCL(WRA)
#undef WRA
    }
    __syncthreads();
    if (g == 0) {
#define RDA(I, A) { float4 v_ = *(const float4*)&cb[(I * 128 + tl) * 4]; \
        A.x += v_.x; A.y += v_.y; A.z += v_.z; A.w += v_.w; }
        ACCL(RDA)
#undef RDA
        // epilogue: combine with base/bias/scalers + graph-norm + BN partials
        float4 bp = *(const float4*)&b_post[l * DD + j0];
        float4 psum = z4, psq = z4;
#define CEPI(I, A0, A1, A2) { \
        int n = n0 + q8 + I; \
        float4 bs = *(const float4*)&base_i[(size_t)n * DD + j0]; \
        float am = amp[n], at = att[n], sn = snorm[n]; \
        float4 o; \
        o.x = (bs.x + bp.x + A0.x + am * A1.x + at * A2.x) * sn; \
        o.y = (bs.y + bp.y + A0.y + am * A1.y + at * A2.y) * sn; \
        o.z = (bs.z + bp.z + A0.z + am * A1.z + at * A2.z) * sn; \
        o.w = (bs.w + bp.w + A0.w + am * A1.w + at * A2.w) * sn; \
        *(float4*)&h_pre[(size_t)n * DD + j0] = o; \
        psum.x += o.x; psum.y += o.y; psum.z += o.z; psum.w += o.w; \
        psq.x = fmaf(o.x, o.x, psq.x); psq.y = fmaf(o.y, o.y, psq.y); \
        psq.z = fmaf(o.z, o.z, psq.z); psq.w = fmaf(o.w, o.w, psq.w); }
        CEPI(0, c0_0, c1_0, c2_0)
        CEPI(1, c0_1, c1_1, c2_1)
        CEPI(2, c0_2, c1_2, c2_2)
        CEPI(3, c0_3, c1_3, c2_3)
        CEPI(4, c0_4, c1_4, c2_4)
        CEPI(5, c0_5, c1_5, c2_5)
        CEPI(6, c0_6, c1_6, c2_6)
        CEPI(7, c0_7, c1_7, c2_7)
#undef CEPI
        float* red = &ag4[0][0];
        *(float4*)&red[tl * 4] = psum;
        *(float4*)&red[512 + tl * 4] = psq;
    }
#undef ACCL
    __syncthreads();
    if (t < 64) {
        float* red = &ag4[0][0];
        float s = 0.f, s2 = 0.f;
#pragma unroll
        for (int qq = 0; qq < 8; ++qq) {
            int idx = (qq * 16 + (t >> 2)) * 4 + (t & 3);
            s += red[idx];
            s2 += red[512 + idx];
        }
        atomicAdd(&bn_acc[l * 128 + t], s);
        atomicAdd(&bn_acc[l * 128 + 64 + t], s2);
    }
}

// D: batchnorm finalize + relu + residual (in-place into h)
__global__ void k_D(const float* __restrict__ h_pre, const float* __restrict__ bn_acc, int l,
                    const float* __restrict__ gamma, const float* __restrict__ beta,
                    float* __restrict__ h) {
    int t = blockIdx.x * 256 + threadIdx.x;   // NN*DD
    int j = t & 63;
    float mu = bn_acc[l * 128 + j] * (1.0f / NN);
    float var = bn_acc[l * 128 + 64 + j] * (1.0f / NN) - mu * mu;
    float inv = rsqrtf(var + BN_EPS);
    float v = gamma[l * DD + j] * (h_pre[t] - mu) * inv + beta[l * DD + j];
    v = fmaxf(v, 0.f);
    h[t] = h[t] + v;
}

// readout: per-graph mean (128 consecutive nodes) + MLP 64->32->16->1
__global__ __launch_bounds__(64) void k_read(const float* __restrict__ h,
                                             const float* __restrict__ W1, const float* __restrict__ b1,
                                             const float* __restrict__ W2, const float* __restrict__ b2,
                                             const float* __restrict__ W3, const float* __restrict__ b3,
                                             float* __restrict__ out) {
    __shared__ float hgs[64];
    __shared__ float o1[32];
    __shared__ float o2[16];
    int g = blockIdx.x, lane = threadIdx.x;
    float acc = 0.f;
    for (int i = 0; i < 128; i++) acc += h[(size_t)(g * 128 + i) * DD + lane];
    hgs[lane] = acc * (1.0f / 128.0f);
    __syncthreads();
    if (lane < 32) {
        float s = b1[lane];
#pragma unroll
        for (int k = 0; k < 64; k++) s = fmaf(hgs[k], W1[k * 32 + lane], s);
        o1[lane] = fmaxf(s, 0.f);
    }
    __syncthreads();
    if (lane < 16) {
        float s = b2[lane];
#pragma unroll
        for (int k = 0; k < 32; k++) s = fmaf(o1[k], W2[k * 16 + lane], s);
        o2[lane] = fmaxf(s, 0.f);
    }
    __syncthreads();
    if (lane == 0) {
        float s = b3[0];
#pragma unroll
        for (int k = 0; k < 16; k++) s = fmaf(o2[k], W3[k], s);
        out[g] = s;
    }
}

// ---------------- launch ----------------

extern "C" void kernel_launch(void* const* d_in, const int* in_sizes, int n_in,
                              void* d_out, int out_size, void* d_ws, size_t ws_size,
                              hipStream_t stream) {
    const int* h_tok = (const int*)d_in[0];
    const int* e_tok = (const int*)d_in[1];
    const int* src = (const int*)d_in[2];
    const int* dst = (const int*)d_in[3];
    // d_in[4] graph_id: structure known (n/128)
    const float* snorm = (const float*)d_in[5];
    const float* emb_h = (const float*)d_in[6];
    const float* emb_e = (const float*)d_in[7];
    const float* W_pre = (const float*)d_in[8];
    const float* b_pre = (const float*)d_in[9];
    const float* W_post = (const float*)d_in[10];
    const float* b_post = (const float*)d_in[11];
    const float* gamma = (const float*)d_in[12];
    const float* beta = (const float*)d_in[13];
    const float* W1 = (const float*)d_in[14];
    const float* b1 = (const float*)d_in[15];
    const float* W2 = (const float*)d_in[16];
    const float* b2 = (const float*)d_in[17];
    const float* W3 = (const float*)d_in[18];
    const float* b3 = (const float*)d_in[19];
    float* out = (float*)d_out;

    char* ws = (char*)d_ws;
    size_t off = 0;
    auto alloc = [&](size_t bytes) {
        void* p = ws + off;
        off += (bytes + 255) & ~(size_t)255;
        return p;
    };
    float* h_cur = (float*)alloc((size_t)NN * DD * 4);
    float* h_pre = (float*)alloc((size_t)NN * DD * 4);
    float* ts = (float*)alloc((size_t)NN * DD * 4);
    float* td = (float*)alloc((size_t)NN * DD * 4);
    float* base_b = (float*)alloc((size_t)NN * DD * 4);
    float* agg = (float*)alloc((size_t)NN * 256 * 4);
    int* deg = (int*)alloc((size_t)NN * 4);
    int* row_start = (int*)alloc((size_t)(NN + 1) * 4);
    int* cursor = (int*)alloc((size_t)NN * 4);
    int* csr = (int*)alloc((size_t)NE * 4);
    float* amp = (float*)alloc((size_t)NN * 4);
    float* att = (float*)alloc((size_t)NN * 4);
    float* invdeg = (float*)alloc((size_t)NN * 4);
    float* bond = (float*)alloc((size_t)NL * 8 * DD * 4);
    float* bn_acc = (float*)alloc((size_t)NL * 128 * 4);

    hipMemsetAsync(deg, 0, (size_t)NN * 4, stream);
    hipMemsetAsync(bn_acc, 0, (size_t)NL * 128 * 4, stream);

    k_embed<<<NN * DD / 256, 256, 0, stream>>>(h_tok, emb_h, h_cur);
    k_deg<<<NE / 256, 256, 0, stream>>>(dst, deg);
    k_scan<<<1, 1024, 0, stream>>>(deg, row_start, cursor, amp, att, invdeg);
    k_scatter<<<NE / 256, 256, 0, stream>>>(src, dst, e_tok, cursor, csr);
    k_bond<<<NL * 8 * DD / 256, 256, 0, stream>>>(emb_e, W_pre, b_pre, bond);

    for (int l = 0; l < NL; l++) {
        k_A<<<NN / 64, 256, 0, stream>>>(h_cur, W_pre, W_post, l, ts, td, base_b);
        k_B<<<NN / 4, 256, 0, stream>>>(ts, td, bond + l * 8 * DD, row_start, csr, invdeg, agg);
        k_C<<<NN / 64, 256, 0, stream>>>(agg, base_b, W_post, b_post, l, amp, att, snorm,
                                         h_pre, bn_acc);
        k_D<<<NN * DD / 256, 256, 0, stream>>>(h_pre, bn_acc, l, gamma, beta, h_cur);
    }
    k_read<<<NG, 64, 0, stream>>>(h_cur, W1, b1, W2, b2, W3, b3, out);
}

// Round 15
// 463.233 us; speedup vs baseline: 1.1020x; 1.1020x over previous
//
#include <hip/hip_runtime.h>
#include <math.h>
#include <float.h>

#define NN 32768
#define NE 524288
#define NG 256
#define DD 64
#define NL 4
#define AVGDLOG 2.8332133340562162f
#define BN_EPS 1e-5f

// ---------------- init kernels ----------------

__global__ void k_deg(const int* __restrict__ dst, int* __restrict__ deg) {
    int e = blockIdx.x * 256 + threadIdx.x;
    if (e < NE) atomicAdd(&deg[dst[e]], 1);
}

__global__ __launch_bounds__(1024) void k_scan(const int* __restrict__ deg,
                                               int* __restrict__ row_start,
                                               int* __restrict__ cursor,
                                               float* __restrict__ amp,
                                               float* __restrict__ att,
                                               float* __restrict__ invdeg) {
    __shared__ int sd[1024];
    int t = threadIdx.x;
    int base = t * 32;
    int loc[32];
    int s = 0;
#pragma unroll
    for (int i = 0; i < 32; i++) { loc[i] = deg[base + i]; s += loc[i]; }
    sd[t] = s;
    __syncthreads();
    for (int off = 1; off < 1024; off <<= 1) {
        int v = (t >= off) ? sd[t - off] : 0;
        __syncthreads();
        sd[t] += v;
        __syncthreads();
    }
    int run = sd[t] - s;   // exclusive prefix
#pragma unroll
    for (int i = 0; i < 32; i++) {
        int idx = base + i;
        row_start[idx] = run;
        cursor[idx] = run;
        int dg = loc[i];
        float d = (float)dg;
        float logd = logf(d + 1.0f);
        amp[idx] = logd * (1.0f / AVGDLOG);
        att[idx] = AVGDLOG / fmaxf(logd, 1e-6f);
        invdeg[idx] = 1.0f / fmaxf(d, 1.0f);
        run += dg;
    }
    if (t == 1023) row_start[NN] = run;
}

__global__ void k_scatter(const int* __restrict__ src, const int* __restrict__ dst,
                          const int* __restrict__ e_tok, int* __restrict__ cursor,
                          int* __restrict__ csr) {
    int e = blockIdx.x * 256 + threadIdx.x;
    int d = dst[e];
    int p = atomicAdd(&cursor[d], 1);
    csr[p] = (src[e] << 3) | (e_tok[e] & 7);
}

// bond_msg[l][r][j] = b_pre[l][j] + sum_k emb_e[r][k] * W_pre[l][128+k][j]
__global__ void k_bond(const float* __restrict__ emb_e, const float* __restrict__ W_pre,
                       const float* __restrict__ b_pre, float* __restrict__ bond) {
    int t = blockIdx.x * 256 + threadIdx.x;   // NL*8*64 = 2048 threads
    int j = t & 63, r = (t >> 6) & 7, l = t >> 9;
    float s = b_pre[l * DD + j];
    const float* w = W_pre + (size_t)l * 192 * DD + 128 * DD + j;
    const float* e = emb_e + r * DD;
#pragma unroll
    for (int k = 0; k < DD; k++) s = fmaf(e[k], w[k * DD], s);
    bond[t] = s;
}

// ---------------- per-layer GEMM kernels ----------------
// r9 proven geometry everywhere: 256 thr, 64x64 tile, grid 512; thread = 4 rows
// x 4 cols, NAMED float4 accs, linear [k][j] W in LDS (conflict-free), A tile
// pad-stride 36/68. NO cross-loop register staging (spills: r5/r7/r10/r12).
// Fusions (r15): prev-layer BN+relu+residual folded into k_A's h staging
// (tile-local RMW of h_cur, no race); embed gather folded into k_A(l=0);
// layer-3 BN folded into k_read. k_B/k_C bodies byte-identical to r9.

#define FMA4(acc, a, wv) \
    acc.x = fmaf(a, wv.x, acc.x); acc.y = fmaf(a, wv.y, acc.y); \
    acc.z = fmaf(a, wv.z, acc.z); acc.w = fmaf(a, wv.w, acc.w);

// A: ts = h@Wpre[0:64], td = h@Wpre[64:128], base = h@Wpost[0:64]. Single K=64 phase.
// l==0: h := emb_h[h_tok] (written to h_cur). l>0: h := h_cur + relu(BN_{l-1}(h_pre))
// (written back to h_cur).
__global__ __launch_bounds__(256) void k_A(const int* __restrict__ h_tok,
                                           const float* __restrict__ emb_h,
                                           const float* __restrict__ h_pre,
                                           float* __restrict__ h_cur,
                                           const float* __restrict__ bn_acc,
                                           const float* __restrict__ gamma,
                                           const float* __restrict__ beta,
                                           const float* __restrict__ W_pre,
                                           const float* __restrict__ W_post, int l,
                                           float* __restrict__ ts, float* __restrict__ td,
                                           float* __restrict__ base_o) {
    __shared__ float wl[3 * 4096];   // [c][k 0..63][j 0..63] linear
    __shared__ float hl[64 * 68];    // [n 0..63][k 0..63] pad-stride 68
    int t = threadIdx.x;
    int j0 = (t & 15) << 2;          // also the staging column quad (256 % 16 == 0)
    int q4 = (t >> 4) << 2;
    int n0 = blockIdx.x * 64;
    const float* W0 = W_pre + (size_t)l * 192 * DD;
    const float* W1 = W0 + 64 * DD;
    const float* W2 = W_post + (size_t)l * 832 * DD;
#pragma unroll
    for (int s = 0; s < 12; ++s) {
        int g = s * 256 + t;             // 0..3071 f4 of W (3 x 64 x 16)
        int c = g >> 10;
        int k = (g >> 4) & 63;
        int c4 = (g & 15) << 2;
        const float* Wc = (c == 0) ? W0 : (c == 1 ? W1 : W2);
        *(float4*)&wl[c * 4096 + k * 64 + c4] = *(const float4*)&Wc[(size_t)k * 64 + c4];
    }
    if (l == 0) {
#pragma unroll
        for (int s = 0; s < 4; ++s) {
            int g = s * 256 + t;         // row = g>>4, col quad = j0
            int row = g >> 4;
            int tok = h_tok[n0 + row];
            float4 v = *(const float4*)&emb_h[(size_t)tok * DD + j0];
            *(float4*)&hl[row * 68 + j0] = v;
            *(float4*)&h_cur[(size_t)(n0 + row) * DD + j0] = v;
        }
    } else {
        int lp = l - 1;
        float mu0, mu1, mu2, mu3, iv0, iv1, iv2, iv3;
        float ga0, ga1, ga2, ga3, be0, be1, be2, be3;
#define BNPAR(I, MU, IV, GA, BE) { \
        float m_ = bn_acc[lp * 128 + j0 + I] * (1.0f / NN); \
        float v_ = bn_acc[lp * 128 + 64 + j0 + I] * (1.0f / NN) - m_ * m_; \
        MU = m_; IV = rsqrtf(v_ + BN_EPS); \
        GA = gamma[lp * DD + j0 + I]; BE = beta[lp * DD + j0 + I]; }
        BNPAR(0, mu0, iv0, ga0, be0)
        BNPAR(1, mu1, iv1, ga1, be1)
        BNPAR(2, mu2, iv2, ga2, be2)
        BNPAR(3, mu3, iv3, ga3, be3)
#undef BNPAR
#pragma unroll
        for (int s = 0; s < 4; ++s) {
            int g = s * 256 + t;
            int row = g >> 4;
            size_t gb = (size_t)(n0 + row) * DD + j0;
            float4 hp = *(const float4*)&h_pre[gb];
            float4 hc = *(const float4*)&h_cur[gb];
            float4 v;
            v.x = hc.x + fmaxf(ga0 * (hp.x - mu0) * iv0 + be0, 0.f);
            v.y = hc.y + fmaxf(ga1 * (hp.y - mu1) * iv1 + be1, 0.f);
            v.z = hc.z + fmaxf(ga2 * (hp.z - mu2) * iv2 + be2, 0.f);
            v.w = hc.w + fmaxf(ga3 * (hp.w - mu3) * iv3 + be3, 0.f);
            *(float4*)&hl[row * 68 + j0] = v;
            *(float4*)&h_cur[gb] = v;
        }
    }
    __syncthreads();
    float4 z4 = make_float4(0.f, 0.f, 0.f, 0.f);
    float4 c0_0 = z4, c0_1 = z4, c0_2 = z4, c0_3 = z4;
    float4 c1_0 = z4, c1_1 = z4, c1_2 = z4, c1_3 = z4;
    float4 c2_0 = z4, c2_1 = z4, c2_2 = z4, c2_3 = z4;
#pragma unroll
    for (int k4 = 0; k4 < 16; ++k4) {
        int ab = k4 << 2;
        float4 av0 = *(const float4*)&hl[(q4 + 0) * 68 + ab];
        float4 av1 = *(const float4*)&hl[(q4 + 1) * 68 + ab];
        float4 av2 = *(const float4*)&hl[(q4 + 2) * 68 + ab];
        float4 av3 = *(const float4*)&hl[(q4 + 3) * 68 + ab];
#define ASTEP(KK, COMP) { \
        int widx = (ab + KK) * 64 + j0; \
        float4 wv0 = *(const float4*)&wl[widx]; \
        float4 wv1 = *(const float4*)&wl[4096 + widx]; \
        float4 wv2 = *(const float4*)&wl[8192 + widx]; \
        FMA4(c0_0, av0.COMP, wv0) FMA4(c1_0, av0.COMP, wv1) FMA4(c2_0, av0.COMP, wv2) \
        FMA4(c0_1, av1.COMP, wv0) FMA4(c1_1, av1.COMP, wv1) FMA4(c2_1, av1.COMP, wv2) \
        FMA4(c0_2, av2.COMP, wv0) FMA4(c1_2, av2.COMP, wv1) FMA4(c2_2, av2.COMP, wv2) \
        FMA4(c0_3, av3.COMP, wv0) FMA4(c1_3, av3.COMP, wv1) FMA4(c2_3, av3.COMP, wv2) }
        ASTEP(0, x) ASTEP(1, y) ASTEP(2, z) ASTEP(3, w)
#undef ASTEP
    }
#define AOUT(I, A0, A1, A2) { \
    size_t n = (size_t)(n0 + q4 + I); \
    *(float4*)&ts[n * DD + j0] = A0; \
    *(float4*)&td[n * DD + j0] = A1; \
    *(float4*)&base_o[n * DD + j0] = A2; }
    AOUT(0, c0_0, c1_0, c2_0)
    AOUT(1, c0_1, c1_1, c2_1)
    AOUT(2, c0_2, c1_2, c2_2)
    AOUT(3, c0_3, c1_3, c2_3)
#undef AOUT
}

// B: per-node aggregation (one wave per node, lane = feature), 8-deep gather unroll
__global__ __launch_bounds__(256) void k_B(const float* __restrict__ ts,
                                           const float* __restrict__ td,
                                           const float* __restrict__ bond_l,
                                           const int* __restrict__ row_start,
                                           const int* __restrict__ csr,
                                           const float* __restrict__ invdeg,
                                           float* __restrict__ agg) {
    int t = threadIdx.x;
    int lane = t & 63;
    int q = __builtin_amdgcn_readfirstlane(t >> 6);
    int n = blockIdx.x * 4 + q;
    int rs = __builtin_amdgcn_readfirstlane(row_start[n]);
    int re = __builtin_amdgcn_readfirstlane(row_start[n + 1]);
    int cnt = re - rs;
    const int* cp = csr + rs;
    float tdv = td[(size_t)n * DD + lane];
    float s1 = 0.f, s2 = 0.f, mx = -FLT_MAX, mn = FLT_MAX;
    int i = 0;
    for (; i + 8 <= cnt; i += 8) {
        int p[8];
#pragma unroll
        for (int u = 0; u < 8; ++u) p[u] = cp[i + u];
        float m[8];
#pragma unroll
        for (int u = 0; u < 8; ++u) m[u] = ts[(size_t)(p[u] >> 3) * DD + lane];
#pragma unroll
        for (int u = 0; u < 8; ++u) m[u] += bond_l[((p[u] & 7) << 6) + lane] + tdv;
#pragma unroll
        for (int u = 0; u < 8; ++u) {
            s1 += m[u]; s2 = fmaf(m[u], m[u], s2);
            mx = fmaxf(mx, m[u]); mn = fminf(mn, m[u]);
        }
    }
    for (; i < cnt; i++) {
        int p0 = cp[i];
        float m0 = ts[(size_t)(p0 >> 3) * DD + lane] + bond_l[((p0 & 7) << 6) + lane] + tdv;
        s1 += m0; s2 = fmaf(m0, m0, s2); mx = fmaxf(mx, m0); mn = fminf(mn, m0);
    }
    float iv = invdeg[n];
    float mean = s1 * iv;
    float var = fmaxf(s2 * iv - mean * mean, 0.f);
    float sd = sqrtf(var + BN_EPS);
    bool has = cnt > 0;
    mx = has ? mx : 0.f;
    mn = has ? mn : 0.f;
    float* ao = agg + (size_t)n * 256;
    ao[lane] = mean;
    ao[64 + lane] = mx;
    ao[128 + lane] = mn;
    ao[192 + lane] = sd;
}

// C: h_pre = (base + b_post + agg@W1c + amp*(agg@W2c) + att*(agg@W3c)) * snorm ; BN partials
// 8 chunks of 32 K, simple 2-phase stage/compute (r9 proven, 53us).
__global__ __launch_bounds__(256) void k_C(const float* __restrict__ agg,
                                           const float* __restrict__ base_i,
                                           const float* __restrict__ W_post,
                                           const float* __restrict__ b_post, int l,
                                           const float* __restrict__ amp,
                                           const float* __restrict__ att,
                                           const float* __restrict__ snorm,
                                           float* __restrict__ h_pre,
                                           float* __restrict__ bn_acc) {
    __shared__ float wl[3 * 2048];   // [c][k 0..31][j 0..63] linear
    __shared__ float ag[64 * 36];    // [n 0..63][k 0..31] pad-stride 36
    int t = threadIdx.x;
    int j0 = (t & 15) << 2;
    int q4 = (t >> 4) << 2;
    int n0 = blockIdx.x * 64;
    const float* Wp = W_post + (size_t)l * 832 * DD;
    float4 z4 = make_float4(0.f, 0.f, 0.f, 0.f);
    float4 c0_0 = z4, c0_1 = z4, c0_2 = z4, c0_3 = z4;
    float4 c1_0 = z4, c1_1 = z4, c1_2 = z4, c1_3 = z4;
    float4 c2_0 = z4, c2_1 = z4, c2_2 = z4, c2_3 = z4;

    for (int kc = 0; kc < 8; ++kc) {
        if (kc) __syncthreads();
#pragma unroll
        for (int s = 0; s < 6; ++s) {
            int g = s * 256 + t;          // 0..1535 f4 of W chunk (3 x 32 x 16)
            int c = g >> 9;
            int k = (g >> 4) & 31;
            int c4 = (g & 15) << 2;
            int rowbase = (c == 0) ? 64 : (c == 1 ? 320 : 576);
            *(float4*)&wl[c * 2048 + k * 64 + c4] =
                *(const float4*)&Wp[(size_t)(rowbase + kc * 32 + k) * 64 + c4];
        }
#pragma unroll
        for (int s = 0; s < 2; ++s) {
            int g = s * 256 + t;          // 0..511 f4 of agg chunk (64 x 8)
            int row = g >> 3;
            int c4 = (g & 7) << 2;
            *(float4*)&ag[row * 36 + c4] =
                *(const float4*)&agg[(size_t)(n0 + row) * 256 + kc * 32 + c4];
        }
        __syncthreads();
#pragma unroll
        for (int k4 = 0; k4 < 8; ++k4) {
            int ab = k4 << 2;
            float4 av0 = *(const float4*)&ag[(q4 + 0) * 36 + ab];
            float4 av1 = *(const float4*)&ag[(q4 + 1) * 36 + ab];
            float4 av2 = *(const float4*)&ag[(q4 + 2) * 36 + ab];
            float4 av3 = *(const float4*)&ag[(q4 + 3) * 36 + ab];
#define CSTEP(KK, COMP) { \
            int widx = (ab + KK) * 64 + j0; \
            float4 wv0 = *(const float4*)&wl[widx]; \
            float4 wv1 = *(const float4*)&wl[2048 + widx]; \
            float4 wv2 = *(const float4*)&wl[4096 + widx]; \
            FMA4(c0_0, av0.COMP, wv0) FMA4(c1_0, av0.COMP, wv1) FMA4(c2_0, av0.COMP, wv2) \
            FMA4(c0_1, av1.COMP, wv0) FMA4(c1_1, av1.COMP, wv1) FMA4(c2_1, av1.COMP, wv2) \
            FMA4(c0_2, av2.COMP, wv0) FMA4(c1_2, av2.COMP, wv1) FMA4(c2_2, av2.COMP, wv2) \
            FMA4(c0_3, av3.COMP, wv0) FMA4(c1_3, av3.COMP, wv1) FMA4(c2_3, av3.COMP, wv2) }
            CSTEP(0, x) CSTEP(1, y) CSTEP(2, z) CSTEP(3, w)
#undef CSTEP
        }
    }

    // epilogue: combine + graph-norm + BN partials
    float4 bp = *(const float4*)&b_post[l * DD + j0];
    float4 psum = z4, psq = z4;
#define CEPI(I, A0, A1, A2) { \
    int n = n0 + q4 + I; \
    float4 bs = *(const float4*)&base_i[(size_t)n * DD + j0]; \
    float am = amp[n], at = att[n], sn = snorm[n]; \
    float4 o; \
    o.x = (bs.x + bp.x + A0.x + am * A1.x + at * A2.x) * sn; \
    o.y = (bs.y + bp.y + A0.y + am * A1.y + at * A2.y) * sn; \
    o.z = (bs.z + bp.z + A0.z + am * A1.z + at * A2.z) * sn; \
    o.w = (bs.w + bp.w + A0.w + am * A1.w + at * A2.w) * sn; \
    *(float4*)&h_pre[(size_t)n * DD + j0] = o; \
    psum.x += o.x; psum.y += o.y; psum.z += o.z; psum.w += o.w; \
    psq.x = fmaf(o.x, o.x, psq.x); psq.y = fmaf(o.y, o.y, psq.y); \
    psq.z = fmaf(o.z, o.z, psq.z); psq.w = fmaf(o.w, o.w, psq.w); }
    CEPI(0, c0_0, c1_0, c2_0)
    CEPI(1, c0_1, c1_1, c2_1)
    CEPI(2, c0_2, c1_2, c2_2)
    CEPI(3, c0_3, c1_3, c2_3)
#undef CEPI
    __syncthreads();   // wl no longer needed as weights
    float* red = wl;
    *(float4*)&red[t * 4] = psum;
    *(float4*)&red[1024 + t * 4] = psq;
    __syncthreads();
    if (t < 64) {
        float s = 0.f, s2 = 0.f;
#pragma unroll
        for (int qq = 0; qq < 16; ++qq) {
            int tt = qq * 16 + (t >> 2);
            s += red[tt * 4 + (t & 3)];
            s2 += red[1024 + tt * 4 + (t & 3)];
        }
        atomicAdd(&bn_acc[l * 128 + t], s);
        atomicAdd(&bn_acc[l * 128 + 64 + t], s2);
    }
}

// readout (fused with layer-3 BN+relu+residual): per-graph mean + MLP 64->32->16->1
__global__ __launch_bounds__(64) void k_read(const float* __restrict__ h_pre,
                                             const float* __restrict__ h_cur,
                                             const float* __restrict__ bn_acc,
                                             const float* __restrict__ gamma,
                                             const float* __restrict__ beta,
                                             const float* __restrict__ W1, const float* __restrict__ b1,
                                             const float* __restrict__ W2, const float* __restrict__ b2,
                                             const float* __restrict__ W3, const float* __restrict__ b3,
                                             float* __restrict__ out) {
    __shared__ float hgs[64];
    __shared__ float o1[32];
    __shared__ float o2[16];
    int g = blockIdx.x, lane = threadIdx.x;
    int lp = NL - 1;
    float mu = bn_acc[lp * 128 + lane] * (1.0f / NN);
    float va = bn_acc[lp * 128 + 64 + lane] * (1.0f / NN) - mu * mu;
    float iv = rsqrtf(va + BN_EPS);
    float ga = gamma[lp * DD + lane], be = beta[lp * DD + lane];
    float acc = 0.f;
    for (int i = 0; i < 128; i++) {
        size_t idx = (size_t)(g * 128 + i) * DD + lane;
        float v = h_cur[idx] + fmaxf(ga * (h_pre[idx] - mu) * iv + be, 0.f);
        acc += v;
    }
    hgs[lane] = acc * (1.0f / 128.0f);
    __syncthreads();
    if (lane < 32) {
        float s = b1[lane];
#pragma unroll
        for (int k = 0; k < 64; k++) s = fmaf(hgs[k], W1[k * 32 + lane], s);
        o1[lane] = fmaxf(s, 0.f);
    }
    __syncthreads();
    if (lane < 16) {
        float s = b2[lane];
#pragma unroll
        for (int k = 0; k < 32; k++) s = fmaf(o1[k], W2[k * 16 + lane], s);
        o2[lane] = fmaxf(s, 0.f);
    }
    __syncthreads();
    if (lane == 0) {
        float s = b3[0];
#pragma unroll
        for (int k = 0; k < 16; k++) s = fmaf(o2[k], W3[k], s);
        out[g] = s;
    }
}

// ---------------- launch ----------------

extern "C" void kernel_launch(void* const* d_in, const int* in_sizes, int n_in,
                              void* d_out, int out_size, void* d_ws, size_t ws_size,
                              hipStream_t stream) {
    const int* h_tok = (const int*)d_in[0];
    const int* e_tok = (const int*)d_in[1];
    const int* src = (const int*)d_in[2];
    const int* dst = (const int*)d_in[3];
    // d_in[4] graph_id: structure known (n/128)
    const float* snorm = (const float*)d_in[5];
    const float* emb_h = (const float*)d_in[6];
    const float* emb_e = (const float*)d_in[7];
    const float* W_pre = (const float*)d_in[8];
    const float* b_pre = (const float*)d_in[9];
    const float* W_post = (const float*)d_in[10];
    const float* b_post = (const float*)d_in[11];
    const float* gamma = (const float*)d_in[12];
    const float* beta = (const float*)d_in[13];
    const float* W1 = (const float*)d_in[14];
    const float* b1 = (const float*)d_in[15];
    const float* W2 = (const float*)d_in[16];
    const float* b2 = (const float*)d_in[17];
    const float* W3 = (const float*)d_in[18];
    const float* b3 = (const float*)d_in[19];
    float* out = (float*)d_out;

    char* ws = (char*)d_ws;
    size_t off = 0;
    auto alloc = [&](size_t bytes) {
        void* p = ws + off;
        off += (bytes + 255) & ~(size_t)255;
        return p;
    };
    float* h_cur = (float*)alloc((size_t)NN * DD * 4);
    float* h_pre = (float*)alloc((size_t)NN * DD * 4);
    float* ts = (float*)alloc((size_t)NN * DD * 4);
    float* td = (float*)alloc((size_t)NN * DD * 4);
    float* base_b = (float*)alloc((size_t)NN * DD * 4);
    float* agg = (float*)alloc((size_t)NN * 256 * 4);
    int* deg = (int*)alloc((size_t)NN * 4);
    int* row_start = (int*)alloc((size_t)(NN + 1) * 4);
    int* cursor = (int*)alloc((size_t)NN * 4);
    int* csr = (int*)alloc((size_t)NE * 4);
    float* amp = (float*)alloc((size_t)NN * 4);
    float* att = (float*)alloc((size_t)NN * 4);
    float* invdeg = (float*)alloc((size_t)NN * 4);
    float* bond = (float*)alloc((size_t)NL * 8 * DD * 4);
    float* bn_acc = (float*)alloc((size_t)NL * 128 * 4);

    hipMemsetAsync(deg, 0, (size_t)NN * 4, stream);
    hipMemsetAsync(bn_acc, 0, (size_t)NL * 128 * 4, stream);

    k_deg<<<NE / 256, 256, 0, stream>>>(dst, deg);
    k_scan<<<1, 1024, 0, stream>>>(deg, row_start, cursor, amp, att, invdeg);
    k_scatter<<<NE / 256, 256, 0, stream>>>(src, dst, e_tok, cursor, csr);
    k_bond<<<NL * 8 * DD / 256, 256, 0, stream>>>(emb_e, W_pre, b_pre, bond);

    for (int l = 0; l < NL; l++) {
        k_A<<<NN / 64, 256, 0, stream>>>(h_tok, emb_h, h_pre, h_cur, bn_acc, gamma, beta,
                                         W_pre, W_post, l, ts, td, base_b);
        k_B<<<NN / 4, 256, 0, stream>>>(ts, td, bond + l * 8 * DD, row_start, csr, invdeg, agg);
        k_C<<<NN / 64, 256, 0, stream>>>(agg, base_b, W_post, b_post, l, amp, att, snorm,
                                         h_pre, bn_acc);
    }
    k_read<<<NG, 64, 0, stream>>>(h_pre, h_cur, bn_acc, gamma, beta,
                                  W1, b1, W2, b2, W3, b3, out);
}